// Round 4
// baseline (489.641 us; speedup 1.0000x reference)
//
#include <hip/hip_runtime.h>

typedef __bf16 bf16;
typedef __bf16 bf16x8 __attribute__((ext_vector_type(8)));
typedef __bf16 bf16x4 __attribute__((ext_vector_type(4)));
typedef float  f32x4  __attribute__((ext_vector_type(4)));

#define MFMA16(A,B,C) __builtin_amdgcn_mfma_f32_16x16x32_bf16(A,B,C,0,0,0)

static constexpr int BATCH = 2, HH = 112, WW = 112, CC = 192;
static constexpr int LL = HH*WW;              // 12544
static constexpr int NT = 784;                // tokens per window (112*7)
static constexpr float SCALE = 0.2041241452319315f;   // 24^-0.5

// ---------------- f32 -> bf16 weight conversion with row padding ----------------
__global__ __launch_bounds__(256) void cvtpad_kernel(const float* __restrict__ src,
    bf16* __restrict__ dst, int rows_src, int K, int total)
{
  int i = (blockIdx.x*256 + threadIdx.x)*4;
  if (i >= total) return;
  int r = i / K;                  // K % 4 == 0, i % 4 == 0 -> same row for all 4
  bf16x4 o;
  if (r < rows_src) {
    float4 v = *(const float4*)(src+i);
    o[0]=(bf16)v.x; o[1]=(bf16)v.y; o[2]=(bf16)v.z; o[3]=(bf16)v.w;
  } else { o[0]=o[1]=o[2]=o[3]=(bf16)0.0f; }
  *(bf16x4*)(dst+i) = o;
}

// ---------------- LayerNorm over C=192, one wave per row ----------------
__global__ __launch_bounds__(256) void ln_kernel(const float* __restrict__ in,
    const float* __restrict__ w, const float* __restrict__ b, bf16* __restrict__ out)
{
  int row  = blockIdx.x*4 + (threadIdx.x>>6);
  int lane = threadIdx.x & 63;
  size_t base = (size_t)row*CC;
  float x0=in[base+lane], x1=in[base+lane+64], x2=in[base+lane+128];
  float s = x0+x1+x2;
  #pragma unroll
  for (int o=32;o>=1;o>>=1) s += __shfl_xor(s,o,64);
  float mu = s*(1.0f/CC);
  float d0=x0-mu,d1=x1-mu,d2=x2-mu;
  float v = d0*d0+d1*d1+d2*d2;
  #pragma unroll
  for (int o=32;o>=1;o>>=1) v += __shfl_xor(v,o,64);
  float rstd = rsqrtf(v*(1.0f/CC)+1e-5f);
  out[base+lane]     = (bf16)(d0*rstd*w[lane]     +b[lane]);
  out[base+lane+64]  = (bf16)(d1*rstd*w[lane+64]  +b[lane+64]);
  out[base+lane+128] = (bf16)(d2*rstd*w[lane+128] +b[lane+128]);
}

// ---------------- GEMM 128x128: out[M,Nout] = A[M,K] * W[Npad,K]^T (+epilogue) ----------------
// EPI 0: qkv (scale q cols<192, bf16 out), 1: proj(+bias + res_f32 -> f32)
// EPI 2: fc1(+bias + gelu, bf16 out),     3: fc2(+bias + res_f32 -> f32)
template<int EPI>
__global__ __launch_bounds__(256) void gemm_kernel(
    const bf16* __restrict__ A, const bf16* __restrict__ W, int K, int Nout,
    const float* __restrict__ bias, const float* __restrict__ resf,
    bf16* __restrict__ outb, float* __restrict__ outf)
{
  __shared__ __align__(16) bf16 As[128*72];
  __shared__ __align__(16) bf16 Bs[128*72];
  int m0 = blockIdx.x*128, n0 = blockIdx.y*128;
  int tid = threadIdx.x;
  int lane = tid&63, li = lane&15, quad = lane>>4;
  int wave = tid>>6, wm = wave>>1, wn = wave&1;
  int sr = tid>>1, sc = (tid&1)*32;
  f32x4 acc[4][4] = {};
  for (int k0 = 0; k0 < K; k0 += 64) {
    __syncthreads();
    const bf16* ga = A + (size_t)(m0+sr)*K + k0 + sc;
    const bf16* gb = W + (size_t)(n0+sr)*K + k0 + sc;
    *(bf16x8*)&As[sr*72+sc]    = *(const bf16x8*)ga;
    *(bf16x8*)&As[sr*72+sc+8]  = *(const bf16x8*)(ga+8);
    *(bf16x8*)&As[sr*72+sc+16] = *(const bf16x8*)(ga+16);
    *(bf16x8*)&As[sr*72+sc+24] = *(const bf16x8*)(ga+24);
    *(bf16x8*)&Bs[sr*72+sc]    = *(const bf16x8*)gb;
    *(bf16x8*)&Bs[sr*72+sc+8]  = *(const bf16x8*)(gb+8);
    *(bf16x8*)&Bs[sr*72+sc+16] = *(const bf16x8*)(gb+16);
    *(bf16x8*)&Bs[sr*72+sc+24] = *(const bf16x8*)(gb+24);
    __syncthreads();
    #pragma unroll
    for (int kk=0;kk<2;kk++){
      bf16x8 af[4], bfr[4];
      #pragma unroll
      for (int i=0;i<4;i++)
        af[i] = *(const bf16x8*)&As[(wm*64+i*16+li)*72 + kk*32 + quad*8];
      #pragma unroll
      for (int j=0;j<4;j++)
        bfr[j] = *(const bf16x8*)&Bs[(wn*64+j*16+li)*72 + kk*32 + quad*8];
      #pragma unroll
      for (int i=0;i<4;i++)
        #pragma unroll
        for (int j=0;j<4;j++)
          acc[i][j] = MFMA16(af[i], bfr[j], acc[i][j]);
    }
  }
  #pragma unroll
  for (int i=0;i<4;i++)
  #pragma unroll
  for (int j=0;j<4;j++){
    int col = n0 + wn*64 + j*16 + li;
    if (col >= Nout) continue;
    float bv = (EPI==0) ? 0.0f : bias[col];
    #pragma unroll
    for (int r=0;r<4;r++){
      int row = m0 + wm*64 + i*16 + quad*4 + r;
      float v = acc[i][j][r] + bv;
      size_t off = (size_t)row*Nout + col;
      if (EPI==0)      { if (col < CC) v *= SCALE; outb[off] = (bf16)v; }
      else if (EPI==2) { v = 0.5f*v*(1.0f+erff(v*0.70710678118654752f)); outb[off] = (bf16)v; }
      else             { v += resf[off]; outf[off] = v; }
    }
  }
}

// ---------------- position-bias MLP (tiny) ----------------
__device__ __forceinline__ void ln6_relu(float* v, const float* w, const float* b){
  float mu=0;
  #pragma unroll
  for (int i=0;i<6;i++) mu += v[i];
  mu *= (1.0f/6.0f);
  float var=0;
  #pragma unroll
  for (int i=0;i<6;i++){ float d=v[i]-mu; var += d*d; }
  var *= (1.0f/6.0f);
  float rstd = rsqrtf(var + 1e-5f);
  #pragma unroll
  for (int i=0;i<6;i++){ float t=(v[i]-mu)*rstd*w[i]+b[i]; v[i] = t>0.f? t:0.f; }
}
__device__ __forceinline__ void fc66(const float* in, float* out, const float* w, const float* b){
  #pragma unroll
  for (int i=0;i<6;i++){
    float s=b[i];
    #pragma unroll
    for (int j=0;j<6;j++) s += in[j]*w[i*6+j];
    out[i]=s;
  }
}
__global__ __launch_bounds__(256) void pos_mlp_kernel(
    const float* pw, const float* pb, const float* l1w, const float* l1b,
    const float* f1w, const float* f1b, const float* l2w, const float* l2b,
    const float* f2w, const float* f2b, const float* l3w, const float* l3b,
    const float* f3w, const float* f3b, float* __restrict__ posb)
{
  int gid = blockIdx.x*256 + threadIdx.x;
  if (gid >= 2*2899) return;
  int br = gid / 2899, r = gid % 2899;
  int Hsp = br? 7:112, Wsp = br?112:7;
  int lpw = 2*Wsp-1;
  int iph = r / lpw, ipw = r % lpw;
  float c0 = (float)(iph - (Hsp-1)), c1 = (float)(ipw - (Wsp-1));
  float v[6], t[6];
  #pragma unroll
  for (int i=0;i<6;i++)
    v[i] = c0*pw[br*12+i*2] + c1*pw[br*12+i*2+1] + pb[br*6+i];
  ln6_relu(v, l1w+br*6, l1b+br*6); fc66(v, t, f1w+br*36, f1b+br*6);
  ln6_relu(t, l2w+br*6, l2b+br*6); fc66(t, v, f2w+br*36, f2b+br*6);
  ln6_relu(v, l3w+br*6, l3b+br*6);
  #pragma unroll
  for (int h=0;h<4;h++){
    float s=f3b[br*4+h];
    #pragma unroll
    for (int j=0;j<6;j++) s += v[j]*f3w[br*24+h*6+j];
    posb[(size_t)(br*2899 + r)*4 + h] = s;
  }
}

// ---------------- expand bias table -> rpbT[br][h][j][i] (bf16) ----------------
__global__ __launch_bounds__(256) void rpb_kernel(const float* __restrict__ posb,
                                                  bf16* __restrict__ rpb)
{
  int bid = blockIdx.x;                 // (br*4+h)*784 + j
  int brh = bid / NT, j = bid % NT;
  int br = brh >> 2, h = brh & 3;
  int Hsp = br?7:112, Wsp = br?112:7, lpw = 2*Wsp-1;
  int rhj, rwj;
  if (br==0) { rhj = j/7; rwj = j - rhj*7; } else { rhj = j/112; rwj = j - rhj*112; }
  const float* pbt = posb + (size_t)br*2899*4;
  bf16* dst = rpb + (size_t)bid*NT;
  for (int i = threadIdx.x; i < NT; i += 256) {
    int rhi, rwi;
    if (br==0) { rhi = i/7; rwi = i - rhi*7; } else { rhi = i/112; rwi = i - rhi*112; }
    int idx = (rhi - rhj + Hsp-1)*lpw + (rwi - rwj + Wsp-1);
    dst[i] = (bf16)pbt[idx*4 + h];
  }
}

// ---------------- flash attention, one block per (br,b,window,head) ----------------
__device__ __forceinline__ int tok2l(int br, int t, int w) {
  if (br == 0) return (t/7)*WW + w*7 + (t - (t/7)*7);
  int th = t/112; return (w*7 + th)*WW + (t - th*112);
}

__global__ __launch_bounds__(512) void attn_kernel(const bf16* __restrict__ qkv,
    const bf16* __restrict__ rpb, bf16* __restrict__ out)
{
  __shared__ __align__(16) bf16 Ks[832*40];    // [key 832][d 40], d>=24 zero
  __shared__ __align__(16) bf16 Vt[32*840];    // [d 32][key 840], row 24 = ones
  __shared__ __align__(16) bf16 Ps[8][32*72];  // per-wave P [i 32][key 72]
  int bid = blockIdx.x;
  int br = bid & 1, h = (bid>>1)&3, w = (bid>>3)&15, b = bid>>7;  // (br,h)=bid&7 -> XCD
  int tid = threadIdx.x;
  int lane = tid&63, li = lane&15, quad = lane>>4, wave = tid>>6;
  size_t qbase = (size_t)b*LL*576;
  int coff = br*96 + h*24;
  // zero LDS (pads)
  for (int c = tid; c < (832*40)/8; c += 512) ((int4*)Ks)[c] = make_int4(0,0,0,0);
  for (int c = tid; c < (32*840)/8; c += 512) ((int4*)Vt)[c] = make_int4(0,0,0,0);
  __syncthreads();
  // stage K
  for (int c = tid; c < NT*3; c += 512) {
    int j = c/3, p = c - j*3;
    int l = tok2l(br, j, w);
    *(bf16x8*)&Ks[j*40 + p*8] =
        *(const bf16x8*)(qkv + qbase + (size_t)l*576 + 192 + coff + p*8);
  }
  // stage V transposed + ones row (softmax denominator via MFMA)
  for (int j = tid; j < NT; j += 512) {
    int l = tok2l(br, j, w);
    const bf16* src = qkv + qbase + (size_t)l*576 + 384 + coff;
    bf16x8 v0 = *(const bf16x8*)src;
    bf16x8 v1 = *(const bf16x8*)(src+8);
    bf16x8 v2 = *(const bf16x8*)(src+16);
    #pragma unroll
    for (int d=0; d<8; d++){
      Vt[d*840 + j]      = v0[d];
      Vt[(8+d)*840 + j]  = v1[d];
      Vt[(16+d)*840 + j] = v2[d];
    }
    Vt[24*840 + j] = (bf16)1.0f;
  }
  __syncthreads();
  const bf16* rpbh = rpb + (size_t)(br*4 + h)*NT*NT;

  for (int qg = wave; qg < 25; qg += 8) {      // 32 q-rows per group
    bf16x8 qf[2]; int iu[2];
    #pragma unroll
    for (int t=0;t<2;t++){
      iu[t] = qg*32 + t*16 + li;
      int ic = iu[t] < NT ? iu[t] : NT-1;
      int l = tok2l(br, ic, w);
      qf[t] = *(const bf16x8*)(qkv + qbase + (size_t)l*576 + coff + quad*8);
    }
    int icol0 = iu[0] < NT ? iu[0] : NT-1;
    int icol1 = iu[1] < NT ? iu[1] : NT-1;
    f32x4 O[2][2] = {};

    // bias prefetch buffers (bf16), loaded coalesced from rpbT[j][i]
    bf16 pbA0[16], pbA1[16], pbB0[16], pbB1[16];
    auto ldb = [&](int kc, bf16* d0, bf16* d1){
      #pragma unroll
      for (int kt=0;kt<4;kt++)
        #pragma unroll
        for (int r=0;r<4;r++){
          int n = kt*4+r;
          if (kc==12 && kt>0) { d0[n]=(bf16)(-40.0f); d1[n]=(bf16)(-40.0f); }
          else {
            int j = kc*64 + kt*16 + quad*4 + r;
            d0[n] = rpbh[(size_t)j*NT + icol0];
            d1[n] = rpbh[(size_t)j*NT + icol1];
          }
        }
    };
    auto body = [&](int kb, const bf16* c0, const bf16* c1){
      bf16x8 kf[4];
      #pragma unroll
      for (int kt=0;kt<4;kt++)
        kf[kt] = *(const bf16x8*)&Ks[(kb + kt*16 + li)*40 + quad*8];
      f32x4 S0[4] = {{0,0,0,0},{0,0,0,0},{0,0,0,0},{0,0,0,0}};
      f32x4 S1[4] = {{0,0,0,0},{0,0,0,0},{0,0,0,0},{0,0,0,0}};
      #pragma unroll
      for (int kt=0;kt<4;kt++){
        S0[kt] = MFMA16(kf[kt], qf[0], S0[kt]);   // S^T = K*Q^T
        S1[kt] = MFMA16(kf[kt], qf[1], S1[kt]);
      }
      #pragma unroll
      for (int kt=0;kt<4;kt++){
        bf16x4 p0, p1;
        #pragma unroll
        for (int r=0;r<4;r++){
          p0[r] = (bf16)__expf(S0[kt][r] + (float)c0[kt*4+r]);
          p1[r] = (bf16)__expf(S1[kt][r] + (float)c1[kt*4+r]);
        }
        *(bf16x4*)&Ps[wave][li*72      + kt*16 + quad*4] = p0;
        *(bf16x4*)&Ps[wave][(16+li)*72 + kt*16 + quad*4] = p1;
      }
      asm volatile("s_waitcnt lgkmcnt(0)" ::: "memory");
      #pragma unroll
      for (int kk=0;kk<2;kk++){
        bf16x8 pf0 = *(const bf16x8*)&Ps[wave][li*72      + kk*32 + quad*8];
        bf16x8 pf1 = *(const bf16x8*)&Ps[wave][(16+li)*72 + kk*32 + quad*8];
        #pragma unroll
        for (int dt=0;dt<2;dt++){
          bf16x8 vf = *(const bf16x8*)&Vt[(dt*16+li)*840 + kb + kk*32 + quad*8];
          O[0][dt] = MFMA16(vf, pf0, O[0][dt]);       // O^T = Vt * P^T
          O[1][dt] = MFMA16(vf, pf1, O[1][dt]);
        }
      }
    };

    ldb(0, pbA0, pbA1);
    #pragma unroll
    for (int kc2 = 0; kc2 < 13; kc2 += 2) {
      if (kc2+1 < 13) ldb(kc2+1, pbB0, pbB1);
      body(kc2*64, pbA0, pbA1);
      if (kc2+1 < 13) {
        if (kc2+2 < 13) ldb(kc2+2, pbA0, pbA1);
        body((kc2+1)*64, pbB0, pbB1);
      }
    }

    #pragma unroll
    for (int qt=0;qt<2;qt++){
      float lsum = __shfl(O[qt][1][0], 32+li, 64);    // ones-row (d=24) holds l_i
      float inv = 1.0f/lsum;
      int ii = iu[qt];
      if (ii < NT) {
        int l = tok2l(br, ii, w);
        bf16* dst = out + ((size_t)(b*LL + l))*CC + coff;
        #pragma unroll
        for (int dt=0;dt<2;dt++)
          #pragma unroll
          for (int r=0;r<4;r++){
            int d = dt*16 + quad*4 + r;
            if (d < 24) dst[d] = (bf16)(O[qt][dt][r]*inv);
          }
      }
    }
  }
}

// ---------------- host launcher ----------------
extern "C" void kernel_launch(void* const* d_in, const int* in_sizes, int n_in,
                              void* d_out, int out_size, void* d_ws, size_t ws_size,
                              hipStream_t stream)
{
  const float* x    = (const float*)d_in[0];
  const float* n1w  = (const float*)d_in[1];
  const float* n1b  = (const float*)d_in[2];
  const float* qkvw = (const float*)d_in[3];
  const float* pjw  = (const float*)d_in[4];
  const float* pjb  = (const float*)d_in[5];
  const float* n2w  = (const float*)d_in[6];
  const float* n2b  = (const float*)d_in[7];
  const float* f1w  = (const float*)d_in[8];
  const float* f1b  = (const float*)d_in[9];
  const float* f2w  = (const float*)d_in[10];
  const float* f2b  = (const float*)d_in[11];

  char* p = (char*)d_ws;
  auto alloc = [&](size_t bytes){ void* r = (void*)p; p += (bytes + 255) & ~(size_t)255; return r; };
  bf16*  img  = (bf16*) alloc((size_t)25088*192*2);
  bf16*  qkvb = (bf16*) alloc((size_t)25088*576*2);
  bf16*  attn = (bf16*) alloc((size_t)25088*192*2);
  float* x2   = (float*)alloc((size_t)25088*192*4);
  bf16*  y    = (bf16*) alloc((size_t)25088*192*2);
  bf16*  hbuf = (bf16*) alloc((size_t)25088*768*2);
  float* posb = (float*)alloc((size_t)2*2899*4*4);
  bf16*  rpbb = (bf16*) alloc((size_t)2*4*784*784*2);
  bf16*  qkvw_b = (bf16*)alloc((size_t)640*192*2);   // padded 576->640
  bf16*  pjw_b  = (bf16*)alloc((size_t)256*192*2);   // padded 192->256
  bf16*  f1w_b  = (bf16*)alloc((size_t)768*192*2);   // exact
  bf16*  f2w_b  = (bf16*)alloc((size_t)256*768*2);   // padded 192->256
  float* outp = (float*)d_out;

  cvtpad_kernel<<<(640*192/4+255)/256,256,0,stream>>>(qkvw, qkvw_b, 576, 192, 640*192);
  cvtpad_kernel<<<(256*192/4+255)/256,256,0,stream>>>(pjw,  pjw_b,  192, 192, 256*192);
  cvtpad_kernel<<<(768*192/4+255)/256,256,0,stream>>>(f1w,  f1w_b,  768, 192, 768*192);
  cvtpad_kernel<<<(256*768/4+255)/256,256,0,stream>>>(f2w,  f2w_b,  192, 768, 256*768);

  ln_kernel<<<6272,256,0,stream>>>(x, n1w, n1b, img);
  gemm_kernel<0><<<dim3(196,5),256,0,stream>>>(img, qkvw_b, 192, 576,
      nullptr, nullptr, qkvb, nullptr);
  pos_mlp_kernel<<<23,256,0,stream>>>(
      (const float*)d_in[12], (const float*)d_in[13], (const float*)d_in[14],
      (const float*)d_in[15], (const float*)d_in[16], (const float*)d_in[17],
      (const float*)d_in[18], (const float*)d_in[19], (const float*)d_in[20],
      (const float*)d_in[21], (const float*)d_in[22], (const float*)d_in[23],
      (const float*)d_in[24], (const float*)d_in[25], posb);
  rpb_kernel<<<6272,256,0,stream>>>(posb, rpbb);
  attn_kernel<<<256,512,0,stream>>>(qkvb, rpbb, attn);
  gemm_kernel<1><<<dim3(196,2),256,0,stream>>>(attn, pjw_b, 192, 192,
      pjb, x, nullptr, x2);
  ln_kernel<<<6272,256,0,stream>>>(x2, n2w, n2b, y);
  gemm_kernel<2><<<dim3(196,6),256,0,stream>>>(y, f1w_b, 192, 768,
      f1b, nullptr, hbuf, nullptr);
  gemm_kernel<3><<<dim3(196,2),256,0,stream>>>(hbuf, f2w_b, 768, 192,
      f2b, x2, nullptr, outp);
}

// Round 5
// 385.990 us; speedup vs baseline: 1.2685x; 1.2685x over previous
//
#include <hip/hip_runtime.h>

typedef __bf16 bf16;
typedef __bf16 bf16x8 __attribute__((ext_vector_type(8)));
typedef __bf16 bf16x4 __attribute__((ext_vector_type(4)));
typedef float  f32x4  __attribute__((ext_vector_type(4)));

#define MFMA16(A,B,C) __builtin_amdgcn_mfma_f32_16x16x32_bf16(A,B,C,0,0,0)
#define EXP2F(x) __builtin_amdgcn_exp2f(x)

static constexpr int BATCH = 2, HH = 112, WW = 112, CC = 192;
static constexpr int LL = HH*WW;              // 12544
static constexpr int NT = 784;                // tokens per window (112*7)
static constexpr float LOG2E = 1.4426950408889634f;
static constexpr float SCALE = 0.2041241452319315f;   // 24^-0.5
static constexpr float QSCALE = SCALE * LOG2E;        // folded for exp2 softmax

// ---------------- f32 -> bf16 weight conversion ----------------
__global__ __launch_bounds__(256) void cvt_kernel(const float* __restrict__ src,
                                                  bf16* __restrict__ dst, int n)
{
  int i = (blockIdx.x*256 + threadIdx.x)*4;
  if (i < n) {
    float4 v = *(const float4*)(src+i);
    bf16x4 o; o[0]=(bf16)v.x; o[1]=(bf16)v.y; o[2]=(bf16)v.z; o[3]=(bf16)v.w;
    *(bf16x4*)(dst+i) = o;
  }
}

// ---------------- LayerNorm over C=192, one wave per row ----------------
__global__ __launch_bounds__(256) void ln_kernel(const float* __restrict__ in,
    const float* __restrict__ w, const float* __restrict__ b, bf16* __restrict__ out)
{
  int row  = blockIdx.x*4 + (threadIdx.x>>6);
  int lane = threadIdx.x & 63;
  size_t base = (size_t)row*CC;
  float x0=in[base+lane], x1=in[base+lane+64], x2=in[base+lane+128];
  float s = x0+x1+x2;
  #pragma unroll
  for (int o=32;o>=1;o>>=1) s += __shfl_xor(s,o,64);
  float mu = s*(1.0f/CC);
  float d0=x0-mu,d1=x1-mu,d2=x2-mu;
  float v = d0*d0+d1*d1+d2*d2;
  #pragma unroll
  for (int o=32;o>=1;o>>=1) v += __shfl_xor(v,o,64);
  float rstd = rsqrtf(v*(1.0f/CC)+1e-5f);
  out[base+lane]     = (bf16)(d0*rstd*w[lane]     +b[lane]);
  out[base+lane+64]  = (bf16)(d1*rstd*w[lane+64]  +b[lane+64]);
  out[base+lane+128] = (bf16)(d2*rstd*w[lane+128] +b[lane+128]);
}

// ---------------- LDS-free direct GEMM: one 32x32 tile per wave ----------------
// out[M,Nout] = A[M,K] * W[Nout,K]^T.  A/B fragments load coalesced from global
// (16 rows x 64B lines per dwordx4); L2/LLC absorbs reuse; no barriers.
// EPI 0: qkv (scale q cols<192 by QSCALE, bf16 out), 1: proj(+bias+res_f32 -> f32)
// EPI 2: fc1(+bias+gelu, bf16 out),                  3: fc2(+bias+res_f32 -> f32)
template<int EPI, int K>
__global__ __launch_bounds__(256,4) void gemm_direct(
    const bf16* __restrict__ A, const bf16* __restrict__ W, int Nout,
    const float* __restrict__ bias, const float* __restrict__ resf,
    bf16* __restrict__ outb, float* __restrict__ outf)
{
  int tid = threadIdx.x, lane = tid&63, li = lane&15, quad = lane>>4;
  int wave = tid>>6;
  int ntiles = Nout >> 5;
  int id = blockIdx.x*4 + wave;
  int mt = id / ntiles, nt = id - mt*ntiles;
  int m0 = mt*32, n0 = nt*32;
  const bf16* pa = A + (size_t)(m0+li)*K + quad*8;
  const bf16* pb = W + (size_t)(n0+li)*K + quad*8;
  const size_t rs = (size_t)16*K;
  f32x4 acc[2][2] = {};
  #pragma unroll
  for (int k0 = 0; k0 < K; k0 += 32) {
    bf16x8 a0 = *(const bf16x8*)(pa + k0);
    bf16x8 a1 = *(const bf16x8*)(pa + rs + k0);
    bf16x8 b0 = *(const bf16x8*)(pb + k0);
    bf16x8 b1 = *(const bf16x8*)(pb + rs + k0);
    acc[0][0] = MFMA16(a0,b0,acc[0][0]);
    acc[0][1] = MFMA16(a0,b1,acc[0][1]);
    acc[1][0] = MFMA16(a1,b0,acc[1][0]);
    acc[1][1] = MFMA16(a1,b1,acc[1][1]);
  }
  #pragma unroll
  for (int i=0;i<2;i++)
  #pragma unroll
  for (int j=0;j<2;j++){
    int col = n0 + j*16 + li;
    float bv = (EPI==0) ? 0.0f : bias[col];
    #pragma unroll
    for (int r=0;r<4;r++){
      int row = m0 + i*16 + quad*4 + r;
      float v = acc[i][j][r] + bv;
      size_t off = (size_t)row*Nout + col;
      if (EPI==0)      { if (col < CC) v *= QSCALE; outb[off] = (bf16)v; }
      else if (EPI==2) { v = 0.5f*v*(1.0f+erff(v*0.70710678118654752f)); outb[off] = (bf16)v; }
      else             { v += resf[off]; outf[off] = v; }
    }
  }
}

// ---------------- position-bias MLP (tiny) ----------------
__device__ __forceinline__ void ln6_relu(float* v, const float* w, const float* b){
  float mu=0;
  #pragma unroll
  for (int i=0;i<6;i++) mu += v[i];
  mu *= (1.0f/6.0f);
  float var=0;
  #pragma unroll
  for (int i=0;i<6;i++){ float d=v[i]-mu; var += d*d; }
  var *= (1.0f/6.0f);
  float rstd = rsqrtf(var + 1e-5f);
  #pragma unroll
  for (int i=0;i<6;i++){ float t=(v[i]-mu)*rstd*w[i]+b[i]; v[i] = t>0.f? t:0.f; }
}
__device__ __forceinline__ void fc66(const float* in, float* out, const float* w, const float* b){
  #pragma unroll
  for (int i=0;i<6;i++){
    float s=b[i];
    #pragma unroll
    for (int j=0;j<6;j++) s += in[j]*w[i*6+j];
    out[i]=s;
  }
}
__global__ __launch_bounds__(256) void pos_mlp_kernel(
    const float* pw, const float* pb, const float* l1w, const float* l1b,
    const float* f1w, const float* f1b, const float* l2w, const float* l2b,
    const float* f2w, const float* f2b, const float* l3w, const float* l3b,
    const float* f3w, const float* f3b, float* __restrict__ posb)
{
  int gid = blockIdx.x*256 + threadIdx.x;
  if (gid >= 2*2899) return;
  int br = gid / 2899, r = gid % 2899;
  int Hsp = br? 7:112, Wsp = br?112:7;
  int lpw = 2*Wsp-1;
  int iph = r / lpw, ipw = r % lpw;
  float c0 = (float)(iph - (Hsp-1)), c1 = (float)(ipw - (Wsp-1));
  float v[6], t[6];
  #pragma unroll
  for (int i=0;i<6;i++)
    v[i] = c0*pw[br*12+i*2] + c1*pw[br*12+i*2+1] + pb[br*6+i];
  ln6_relu(v, l1w+br*6, l1b+br*6); fc66(v, t, f1w+br*36, f1b+br*6);
  ln6_relu(t, l2w+br*6, l2b+br*6); fc66(t, v, f2w+br*36, f2b+br*6);
  ln6_relu(v, l3w+br*6, l3b+br*6);
  #pragma unroll
  for (int h=0;h<4;h++){
    float s=f3b[br*4+h];
    #pragma unroll
    for (int j=0;j<6;j++) s += v[j]*f3w[br*24+h*6+j];
    posb[(size_t)(br*2899 + r)*4 + h] = s;
  }
}

// ---------------- flash attention, one block per (br,b,window,head) ----------------
__device__ __forceinline__ int tok2l(int br, int t, int w) {
  if (br == 0) return (t/7)*WW + w*7 + (t - (t/7)*7);
  int th = t/112; return (w*7 + th)*WW + (t - th*112);
}
// relative-position code: a_t = h_t*(2*Wsp-1)/... collapsed: a_t = t + (lpw-Wsp)*row
__device__ __forceinline__ int acode(int br, int t) {
  int rh = br ? (((t>>4)*18725)>>17) : ((t*18725)>>17);   // t/112 or t/7, exact for t<784
  return t + (br ? 111 : 6) * rh;
}

__global__ __launch_bounds__(512) void attn_kernel(const bf16* __restrict__ qkv,
    const float* __restrict__ posb, bf16* __restrict__ out)
{
  __shared__ __align__(16) bf16 Ks[832*40];    // [key 832][d 40], d>=24 zero
  __shared__ __align__(16) bf16 Vt[32*840];    // [d 32][key 840], row 24 = ones
  __shared__ __align__(16) bf16 Ps[8][32*72];  // per-wave P [i 32][key 72]
  __shared__ __align__(16) bf16 postab[2904];  // pos table (x log2e) for this (br,h)
  int bid = blockIdx.x;
  int br = bid & 1, h = (bid>>1)&3, w = (bid>>3)&15, b = bid>>7;  // (br,h)=bid&7 -> XCD
  int tid = threadIdx.x;
  int lane = tid&63, li = lane&15, quad = lane>>4, wave = tid>>6;
  size_t qbase = (size_t)b*LL*576;
  int coff = br*96 + h*24;
  // zero LDS (pads)
  for (int c = tid; c < (832*40)/8; c += 512) ((int4*)Ks)[c] = make_int4(0,0,0,0);
  for (int c = tid; c < (32*840)/8; c += 512) ((int4*)Vt)[c] = make_int4(0,0,0,0);
  __syncthreads();
  // stage K
  for (int c = tid; c < NT*3; c += 512) {
    int j = c/3, p = c - j*3;
    int l = tok2l(br, j, w);
    *(bf16x8*)&Ks[j*40 + p*8] =
        *(const bf16x8*)(qkv + qbase + (size_t)l*576 + 192 + coff + p*8);
  }
  // stage V transposed + ones row (softmax denominator via MFMA)
  for (int j = tid; j < NT; j += 512) {
    int l = tok2l(br, j, w);
    const bf16* src = qkv + qbase + (size_t)l*576 + 384 + coff;
    bf16x8 v0 = *(const bf16x8*)src;
    bf16x8 v1 = *(const bf16x8*)(src+8);
    bf16x8 v2 = *(const bf16x8*)(src+16);
    #pragma unroll
    for (int d=0; d<8; d++){
      Vt[d*840 + j]      = v0[d];
      Vt[(8+d)*840 + j]  = v1[d];
      Vt[(16+d)*840 + j] = v2[d];
    }
    Vt[24*840 + j] = (bf16)1.0f;
  }
  // stage pos table (bf16, pre-multiplied by log2e) for this (br,h)
  {
    const float* pb = posb + (size_t)br*2899*4 + h;
    for (int r = tid; r < 2904; r += 512)
      postab[r] = (bf16)(r < 2899 ? pb[(size_t)r*4]*LOG2E : 0.0f);
  }
  __syncthreads();

  // per-wave q-groups: qg = wave + 8*g, g = 0..3 (qg < 25)
  bf16x8 qf[4][2]; int pai[4][2];
  #pragma unroll
  for (int g=0; g<4; g++){
    int qg = wave + 8*g;
    if (qg >= 25) continue;
    #pragma unroll
    for (int t=0;t<2;t++){
      int ii = qg*32 + t*16 + li;
      int ic = ii < NT ? ii : NT-1;
      int l = tok2l(br, ic, w);
      qf[g][t] = *(const bf16x8*)(qkv + qbase + (size_t)l*576 + coff + quad*8);
      pai[g][t] = acode(br, ic) + 1449;
    }
  }
  f32x4 O[4][2][2] = {};

  for (int kc = 0; kc < 13; kc++) {            // 64 keys per chunk (outer!)
    int kb = kc*64;
    // per-lane j-codes for this chunk (shared across all q-groups)
    int ajv[16];
    #pragma unroll
    for (int kt=0;kt<4;kt++)
      #pragma unroll
      for (int r=0;r<4;r++){
        int j = kb + kt*16 + quad*4 + r;
        int jc = j < NT ? j : NT-1;
        ajv[kt*4+r] = acode(br, jc);
      }
    bf16x8 kf[4];
    #pragma unroll
    for (int kt=0;kt<4;kt++)
      kf[kt] = *(const bf16x8*)&Ks[(kb + kt*16 + li)*40 + quad*8];
    bf16x8 vf[2][2];
    #pragma unroll
    for (int dt=0;dt<2;dt++)
      #pragma unroll
      for (int kk=0;kk<2;kk++)
        vf[dt][kk] = *(const bf16x8*)&Vt[(dt*16+li)*840 + kb + kk*32 + quad*8];

    #pragma unroll
    for (int g=0; g<4; g++){
      if (wave + 8*g >= 25) continue;          // wave-uniform skip
      f32x4 S0[4] = {{0,0,0,0},{0,0,0,0},{0,0,0,0},{0,0,0,0}};
      f32x4 S1[4] = {{0,0,0,0},{0,0,0,0},{0,0,0,0},{0,0,0,0}};
      #pragma unroll
      for (int kt=0;kt<4;kt++){
        S0[kt] = MFMA16(kf[kt], qf[g][0], S0[kt]);   // S^T = K*Q^T (log2e folded)
        S1[kt] = MFMA16(kf[kt], qf[g][1], S1[kt]);
      }
      #pragma unroll
      for (int kt=0;kt<4;kt++){
        bf16x4 p0, p1;
        #pragma unroll
        for (int r=0;r<4;r++){
          int n = kt*4+r;
          float b0 = (float)postab[pai[g][0] - ajv[n]];
          float b1 = (float)postab[pai[g][1] - ajv[n]];
          bool valid = (kb + kt*16 + quad*4 + r) < NT;
          p0[r] = (bf16)EXP2F(S0[kt][r] + (valid ? b0 : -55.0f));
          p1[r] = (bf16)EXP2F(S1[kt][r] + (valid ? b1 : -55.0f));
        }
        *(bf16x4*)&Ps[wave][li*72      + kt*16 + quad*4] = p0;
        *(bf16x4*)&Ps[wave][(16+li)*72 + kt*16 + quad*4] = p1;
      }
      asm volatile("s_waitcnt lgkmcnt(0)" ::: "memory");
      #pragma unroll
      for (int kk=0;kk<2;kk++){
        bf16x8 pf0 = *(const bf16x8*)&Ps[wave][li*72      + kk*32 + quad*8];
        bf16x8 pf1 = *(const bf16x8*)&Ps[wave][(16+li)*72 + kk*32 + quad*8];
        #pragma unroll
        for (int dt=0;dt<2;dt++){
          O[g][0][dt] = MFMA16(vf[dt][kk], pf0, O[g][0][dt]);   // O^T = Vt * P^T
          O[g][1][dt] = MFMA16(vf[dt][kk], pf1, O[g][1][dt]);
        }
      }
    }
  }

  #pragma unroll
  for (int g=0; g<4; g++){
    int qg = wave + 8*g;
    if (qg >= 25) continue;
    #pragma unroll
    for (int qt=0;qt<2;qt++){
      float lsum = __shfl(O[g][qt][1][0], 32+li, 64);  // ones-row (d=24) holds l_i
      float inv = 1.0f/lsum;
      int ii = qg*32 + qt*16 + li;
      if (ii < NT) {
        int l = tok2l(br, ii, w);
        bf16* dst = out + ((size_t)(b*LL + l))*CC + coff;
        #pragma unroll
        for (int dt=0;dt<2;dt++)
          #pragma unroll
          for (int r=0;r<4;r++){
            int d = dt*16 + quad*4 + r;
            if (d < 24) dst[d] = (bf16)(O[g][qt][dt][r]*inv);
          }
      }
    }
  }
}

// ---------------- host launcher ----------------
extern "C" void kernel_launch(void* const* d_in, const int* in_sizes, int n_in,
                              void* d_out, int out_size, void* d_ws, size_t ws_size,
                              hipStream_t stream)
{
  const float* x    = (const float*)d_in[0];
  const float* n1w  = (const float*)d_in[1];
  const float* n1b  = (const float*)d_in[2];
  const float* qkvw = (const float*)d_in[3];
  const float* pjw  = (const float*)d_in[4];
  const float* pjb  = (const float*)d_in[5];
  const float* n2w  = (const float*)d_in[6];
  const float* n2b  = (const float*)d_in[7];
  const float* f1w  = (const float*)d_in[8];
  const float* f1b  = (const float*)d_in[9];
  const float* f2w  = (const float*)d_in[10];
  const float* f2b  = (const float*)d_in[11];

  char* p = (char*)d_ws;
  auto alloc = [&](size_t bytes){ void* r = (void*)p; p += (bytes + 255) & ~(size_t)255; return r; };
  bf16*  img  = (bf16*) alloc((size_t)25088*192*2);
  bf16*  qkvb = (bf16*) alloc((size_t)25088*576*2);
  bf16*  attn = (bf16*) alloc((size_t)25088*192*2);
  float* x2   = (float*)alloc((size_t)25088*192*4);
  bf16*  y    = (bf16*) alloc((size_t)25088*192*2);
  bf16*  hbuf = (bf16*) alloc((size_t)25088*768*2);
  float* posb = (float*)alloc((size_t)2*2899*4*4);
  bf16*  qkvw_b = (bf16*)alloc((size_t)576*192*2);
  bf16*  pjw_b  = (bf16*)alloc((size_t)192*192*2);
  bf16*  f1w_b  = (bf16*)alloc((size_t)768*192*2);
  bf16*  f2w_b  = (bf16*)alloc((size_t)192*768*2);
  float* outp = (float*)d_out;

  cvt_kernel<<<108,256,0,stream>>>(qkvw, qkvw_b, 576*192);
  cvt_kernel<<<36, 256,0,stream>>>(pjw,  pjw_b,  192*192);
  cvt_kernel<<<144,256,0,stream>>>(f1w,  f1w_b,  768*192);
  cvt_kernel<<<144,256,0,stream>>>(f2w,  f2w_b,  192*768);

  ln_kernel<<<6272,256,0,stream>>>(x, n1w, n1b, img);
  gemm_direct<0,192><<<3528,256,0,stream>>>(img, qkvw_b, 576,
      nullptr, nullptr, qkvb, nullptr);
  pos_mlp_kernel<<<23,256,0,stream>>>(
      (const float*)d_in[12], (const float*)d_in[13], (const float*)d_in[14],
      (const float*)d_in[15], (const float*)d_in[16], (const float*)d_in[17],
      (const float*)d_in[18], (const float*)d_in[19], (const float*)d_in[20],
      (const float*)d_in[21], (const float*)d_in[22], (const float*)d_in[23],
      (const float*)d_in[24], (const float*)d_in[25], posb);
  attn_kernel<<<256,512,0,stream>>>(qkvb, posb, attn);
  gemm_direct<1,192><<<1176,256,0,stream>>>(attn, pjw_b, 192,
      pjb, x, nullptr, x2);
  ln_kernel<<<6272,256,0,stream>>>(x2, n2w, n2b, y);
  gemm_direct<2,192><<<4704,256,0,stream>>>(y, f1w_b, 768,
      f1b, nullptr, hbuf, nullptr);
  gemm_direct<3,768><<<1176,256,0,stream>>>(hbuf, f2w_b, 192,
      f2b, x2, nullptr, outp);
}

// Round 6
// 356.575 us; speedup vs baseline: 1.3732x; 1.0825x over previous
//
#include <hip/hip_runtime.h>

typedef __bf16 bf16;
typedef __bf16 bf16x8 __attribute__((ext_vector_type(8)));
typedef __bf16 bf16x4 __attribute__((ext_vector_type(4)));
typedef float  f32x4  __attribute__((ext_vector_type(4)));

#define MFMA16(A,B,C) __builtin_amdgcn_mfma_f32_16x16x32_bf16(A,B,C,0,0,0)
#define EXP2F(x) __builtin_amdgcn_exp2f(x)

static constexpr int BATCH = 2, HH = 112, WW = 112, CC = 192;
static constexpr int LL = HH*WW;              // 12544
static constexpr int NT = 784;                // tokens per window (112*7)
static constexpr float LOG2E = 1.4426950408889634f;
static constexpr float SCALE = 0.2041241452319315f;   // 24^-0.5
static constexpr float QSCALE = SCALE * LOG2E;        // folded for exp2 softmax

// ---------------- f32 -> bf16 weight conversion ----------------
__global__ __launch_bounds__(256) void cvt_kernel(const float* __restrict__ src,
                                                  bf16* __restrict__ dst, int n)
{
  int i = (blockIdx.x*256 + threadIdx.x)*4;
  if (i < n) {
    float4 v = *(const float4*)(src+i);
    bf16x4 o; o[0]=(bf16)v.x; o[1]=(bf16)v.y; o[2]=(bf16)v.z; o[3]=(bf16)v.w;
    *(bf16x4*)(dst+i) = o;
  }
}

// ---------------- LayerNorm over C=192, one wave per row ----------------
__global__ __launch_bounds__(256) void ln_kernel(const float* __restrict__ in,
    const float* __restrict__ w, const float* __restrict__ b, bf16* __restrict__ out)
{
  int row  = blockIdx.x*4 + (threadIdx.x>>6);
  int lane = threadIdx.x & 63;
  size_t base = (size_t)row*CC;
  float x0=in[base+lane], x1=in[base+lane+64], x2=in[base+lane+128];
  float s = x0+x1+x2;
  #pragma unroll
  for (int o=32;o>=1;o>>=1) s += __shfl_xor(s,o,64);
  float mu = s*(1.0f/CC);
  float d0=x0-mu,d1=x1-mu,d2=x2-mu;
  float v = d0*d0+d1*d1+d2*d2;
  #pragma unroll
  for (int o=32;o>=1;o>>=1) v += __shfl_xor(v,o,64);
  float rstd = rsqrtf(v*(1.0f/CC)+1e-5f);
  out[base+lane]     = (bf16)(d0*rstd*w[lane]     +b[lane]);
  out[base+lane+64]  = (bf16)(d1*rstd*w[lane+64]  +b[lane+64]);
  out[base+lane+128] = (bf16)(d2*rstd*w[lane+128] +b[lane+128]);
}

// ------------- GEMM, B-in-registers: out[M,Nout] = A[M,K]*W[Nout,K]^T -------------
// Block: 64-col n-tile, M-strip of ITERS*64 rows. B-frags (64n x K) held in
// 96 VGPRs, loaded once. Barrier-free M-loop: 16-row slice per wave per iter:
// K/32 coalesced A loads + 4*K/32 MFMAs + stores. Zero LDS.
// EPI 0: qkv (scale q cols<192 by QSCALE, bf16 out), 1: proj(+bias+res_f32 -> f32)
// EPI 2: fc1(+bias+gelu, bf16 out)
template<int EPI, int K, int ITERS>
__global__ __launch_bounds__(256) void gemm_regB(
    const bf16* __restrict__ A, const bf16* __restrict__ W, int Nout,
    const float* __restrict__ bias, const float* __restrict__ resf,
    bf16* __restrict__ outb, float* __restrict__ outf)
{
  constexpr int KC = K/32;
  int tid = threadIdx.x, lane = tid&63, li = lane&15, quad = lane>>4;
  int wave = tid>>6;
  int n0 = blockIdx.x*64;
  int strip0 = blockIdx.y * (ITERS*64);
  bf16x8 breg[4][KC];
  #pragma unroll
  for (int nf=0;nf<4;nf++){
    const bf16* pw = W + (size_t)(n0+nf*16+li)*K + quad*8;
    #pragma unroll
    for (int k=0;k<KC;k++) breg[nf][k] = *(const bf16x8*)(pw + k*32);
  }
  float bv[4];
  #pragma unroll
  for (int nf=0;nf<4;nf++) bv[nf] = (EPI==0) ? 0.0f : bias[n0+nf*16+li];

  for (int it=0; it<ITERS; it++){
    int rowbase = strip0 + (it*4+wave)*16;
    const bf16* pa = A + (size_t)(rowbase+li)*K + quad*8;
    bf16x8 a[KC];
    #pragma unroll
    for (int k=0;k<KC;k++) a[k] = *(const bf16x8*)(pa + k*32);
    f32x4 acc[4] = {};
    #pragma unroll
    for (int k=0;k<KC;k++)
      #pragma unroll
      for (int nf=0;nf<4;nf++)
        acc[nf] = MFMA16(a[k], breg[nf][k], acc[nf]);
    #pragma unroll
    for (int nf=0;nf<4;nf++){
      int col = n0 + nf*16 + li;
      #pragma unroll
      for (int r=0;r<4;r++){
        int row = rowbase + quad*4 + r;
        float v = acc[nf][r] + bv[nf];
        size_t off = (size_t)row*Nout + col;
        if (EPI==0)      { if (col < CC) v *= QSCALE; outb[off] = (bf16)v; }
        else if (EPI==2) { v = 0.5f*v*(1.0f+erff(v*0.70710678118654752f)); outb[off] = (bf16)v; }
        else             { v += resf[off]; outf[off] = v; }
      }
    }
  }
}

// ------------- fc2 GEMM, B in LDS (K=768): 32-col n-tile -------------
// EPI 3: fc2(+bias + res_f32 -> f32 out)
template<int ITERS>
__global__ __launch_bounds__(256) void gemm_ldsB(
    const bf16* __restrict__ A, const bf16* __restrict__ W, int Nout,
    const float* __restrict__ bias, const float* __restrict__ resf,
    float* __restrict__ outf)
{
  constexpr int K = 768, KC = K/32;   // 24
  __shared__ __align__(16) bf16 Bs[32*776];   // pad 768->776: 2-way-free banks
  int tid = threadIdx.x, lane = tid&63, li = lane&15, quad = lane>>4;
  int wave = tid>>6;
  int n0 = blockIdx.x*32;
  int strip0 = blockIdx.y * (ITERS*64);
  for (int c = tid; c < 32*96; c += 256){
    int r = c/96, cc = c - r*96;
    *(bf16x8*)&Bs[r*776 + cc*8] = *(const bf16x8*)(W + (size_t)(n0+r)*K + cc*8);
  }
  float bv[2];
  #pragma unroll
  for (int nf=0;nf<2;nf++) bv[nf] = bias[n0+nf*16+li];
  __syncthreads();

  for (int it=0; it<ITERS; it++){
    int rowbase = strip0 + (it*4+wave)*16;
    const bf16* pa = A + (size_t)(rowbase+li)*K + quad*8;
    f32x4 acc[2] = {};
    #pragma unroll
    for (int k=0;k<KC;k++){
      bf16x8 a  = *(const bf16x8*)(pa + k*32);
      bf16x8 b0 = *(const bf16x8*)&Bs[li*776      + k*32 + quad*8];
      bf16x8 b1 = *(const bf16x8*)&Bs[(16+li)*776 + k*32 + quad*8];
      acc[0] = MFMA16(a, b0, acc[0]);
      acc[1] = MFMA16(a, b1, acc[1]);
    }
    #pragma unroll
    for (int nf=0;nf<2;nf++){
      int col = n0 + nf*16 + li;
      #pragma unroll
      for (int r=0;r<4;r++){
        int row = rowbase + quad*4 + r;
        size_t off = (size_t)row*Nout + col;
        outf[off] = acc[nf][r] + bv[nf] + resf[off];
      }
    }
  }
}

// ---------------- position-bias MLP (tiny) ----------------
__device__ __forceinline__ void ln6_relu(float* v, const float* w, const float* b){
  float mu=0;
  #pragma unroll
  for (int i=0;i<6;i++) mu += v[i];
  mu *= (1.0f/6.0f);
  float var=0;
  #pragma unroll
  for (int i=0;i<6;i++){ float d=v[i]-mu; var += d*d; }
  var *= (1.0f/6.0f);
  float rstd = rsqrtf(var + 1e-5f);
  #pragma unroll
  for (int i=0;i<6;i++){ float t=(v[i]-mu)*rstd*w[i]+b[i]; v[i] = t>0.f? t:0.f; }
}
__device__ __forceinline__ void fc66(const float* in, float* out, const float* w, const float* b){
  #pragma unroll
  for (int i=0;i<6;i++){
    float s=b[i];
    #pragma unroll
    for (int j=0;j<6;j++) s += in[j]*w[i*6+j];
    out[i]=s;
  }
}
__global__ __launch_bounds__(256) void pos_mlp_kernel(
    const float* pw, const float* pb, const float* l1w, const float* l1b,
    const float* f1w, const float* f1b, const float* l2w, const float* l2b,
    const float* f2w, const float* f2b, const float* l3w, const float* l3b,
    const float* f3w, const float* f3b, float* __restrict__ posb)
{
  int gid = blockIdx.x*256 + threadIdx.x;
  if (gid >= 2*2899) return;
  int br = gid / 2899, r = gid % 2899;
  int Hsp = br? 7:112, Wsp = br?112:7;
  int lpw = 2*Wsp-1;
  int iph = r / lpw, ipw = r % lpw;
  float c0 = (float)(iph - (Hsp-1)), c1 = (float)(ipw - (Wsp-1));
  float v[6], t[6];
  #pragma unroll
  for (int i=0;i<6;i++)
    v[i] = c0*pw[br*12+i*2] + c1*pw[br*12+i*2+1] + pb[br*6+i];
  ln6_relu(v, l1w+br*6, l1b+br*6); fc66(v, t, f1w+br*36, f1b+br*6);
  ln6_relu(t, l2w+br*6, l2b+br*6); fc66(t, v, f2w+br*36, f2b+br*6);
  ln6_relu(v, l3w+br*6, l3b+br*6);
  #pragma unroll
  for (int h=0;h<4;h++){
    float s=f3b[br*4+h];
    #pragma unroll
    for (int j=0;j<6;j++) s += v[j]*f3w[br*24+h*6+j];
    posb[(size_t)(br*2899 + r)*4 + h] = s;
  }
}

// ---------------- flash attention, one block per (br,b,window,head) ----------------
__device__ __forceinline__ int tok2l(int br, int t, int w) {
  if (br == 0) return (t/7)*WW + w*7 + (t - (t/7)*7);
  int th = t/112; return (w*7 + th)*WW + (t - th*112);
}
__device__ __forceinline__ int acode(int br, int t) {
  int rh = br ? (((t>>4)*18725)>>17) : ((t*18725)>>17);   // t/112 or t/7, exact for t<784
  return t + (br ? 111 : 6) * rh;
}

__global__ __launch_bounds__(512) void attn_kernel(const bf16* __restrict__ qkv,
    const float* __restrict__ posb, bf16* __restrict__ out)
{
  __shared__ __align__(16) bf16 Ks[832*40];    // [key 832][d 40], d>=24 zero
  __shared__ __align__(16) bf16 Vt[32*840];    // [d 32][key 840], row 24 = ones
  __shared__ __align__(16) bf16 Ps[8][32*72];  // per-wave P [i 32][key 72]
  __shared__ __align__(16) bf16 postab[2904];  // pos table (x log2e) for this (br,h)
  int bid = blockIdx.x;
  int br = bid & 1, h = (bid>>1)&3, w = (bid>>3)&15, b = bid>>7;  // (br,h)=bid&7 -> XCD
  int tid = threadIdx.x;
  int lane = tid&63, li = lane&15, quad = lane>>4, wave = tid>>6;
  size_t qbase = (size_t)b*LL*576;
  int coff = br*96 + h*24;
  for (int c = tid; c < (832*40)/8; c += 512) ((int4*)Ks)[c] = make_int4(0,0,0,0);
  for (int c = tid; c < (32*840)/8; c += 512) ((int4*)Vt)[c] = make_int4(0,0,0,0);
  __syncthreads();
  for (int c = tid; c < NT*3; c += 512) {
    int j = c/3, p = c - j*3;
    int l = tok2l(br, j, w);
    *(bf16x8*)&Ks[j*40 + p*8] =
        *(const bf16x8*)(qkv + qbase + (size_t)l*576 + 192 + coff + p*8);
  }
  for (int j = tid; j < NT; j += 512) {
    int l = tok2l(br, j, w);
    const bf16* src = qkv + qbase + (size_t)l*576 + 384 + coff;
    bf16x8 v0 = *(const bf16x8*)src;
    bf16x8 v1 = *(const bf16x8*)(src+8);
    bf16x8 v2 = *(const bf16x8*)(src+16);
    #pragma unroll
    for (int d=0; d<8; d++){
      Vt[d*840 + j]      = v0[d];
      Vt[(8+d)*840 + j]  = v1[d];
      Vt[(16+d)*840 + j] = v2[d];
    }
    Vt[24*840 + j] = (bf16)1.0f;
  }
  {
    const float* pb = posb + (size_t)br*2899*4 + h;
    for (int r = tid; r < 2904; r += 512)
      postab[r] = (bf16)(r < 2899 ? pb[(size_t)r*4]*LOG2E : 0.0f);
  }
  __syncthreads();

  bf16x8 qf[4][2]; int pai[4][2];
  #pragma unroll
  for (int g=0; g<4; g++){
    int qg = wave + 8*g;
    if (qg >= 25) continue;
    #pragma unroll
    for (int t=0;t<2;t++){
      int ii = qg*32 + t*16 + li;
      int ic = ii < NT ? ii : NT-1;
      int l = tok2l(br, ic, w);
      qf[g][t] = *(const bf16x8*)(qkv + qbase + (size_t)l*576 + coff + quad*8);
      pai[g][t] = acode(br, ic) + 1449;
    }
  }
  f32x4 O[4][2][2] = {};

  for (int kc = 0; kc < 13; kc++) {
    int kb = kc*64;
    int ajv[16];
    #pragma unroll
    for (int kt=0;kt<4;kt++)
      #pragma unroll
      for (int r=0;r<4;r++){
        int j = kb + kt*16 + quad*4 + r;
        int jc = j < NT ? j : NT-1;
        ajv[kt*4+r] = acode(br, jc);
      }
    bf16x8 kf[4];
    #pragma unroll
    for (int kt=0;kt<4;kt++)
      kf[kt] = *(const bf16x8*)&Ks[(kb + kt*16 + li)*40 + quad*8];
    bf16x8 vf[2][2];
    #pragma unroll
    for (int dt=0;dt<2;dt++)
      #pragma unroll
      for (int kk=0;kk<2;kk++)
        vf[dt][kk] = *(const bf16x8*)&Vt[(dt*16+li)*840 + kb + kk*32 + quad*8];

    #pragma unroll
    for (int g=0; g<4; g++){
      if (wave + 8*g >= 25) continue;
      f32x4 S0[4] = {{0,0,0,0},{0,0,0,0},{0,0,0,0},{0,0,0,0}};
      f32x4 S1[4] = {{0,0,0,0},{0,0,0,0},{0,0,0,0},{0,0,0,0}};
      #pragma unroll
      for (int kt=0;kt<4;kt++){
        S0[kt] = MFMA16(kf[kt], qf[g][0], S0[kt]);
        S1[kt] = MFMA16(kf[kt], qf[g][1], S1[kt]);
      }
      #pragma unroll
      for (int kt=0;kt<4;kt++){
        bf16x4 p0, p1;
        #pragma unroll
        for (int r=0;r<4;r++){
          int n = kt*4+r;
          float b0 = (float)postab[pai[g][0] - ajv[n]];
          float b1 = (float)postab[pai[g][1] - ajv[n]];
          bool valid = (kb + kt*16 + quad*4 + r) < NT;
          p0[r] = (bf16)EXP2F(S0[kt][r] + (valid ? b0 : -55.0f));
          p1[r] = (bf16)EXP2F(S1[kt][r] + (valid ? b1 : -55.0f));
        }
        *(bf16x4*)&Ps[wave][li*72      + kt*16 + quad*4] = p0;
        *(bf16x4*)&Ps[wave][(16+li)*72 + kt*16 + quad*4] = p1;
      }
      asm volatile("s_waitcnt lgkmcnt(0)" ::: "memory");
      #pragma unroll
      for (int kk=0;kk<2;kk++){
        bf16x8 pf0 = *(const bf16x8*)&Ps[wave][li*72      + kk*32 + quad*8];
        bf16x8 pf1 = *(const bf16x8*)&Ps[wave][(16+li)*72 + kk*32 + quad*8];
        #pragma unroll
        for (int dt=0;dt<2;dt++){
          O[g][0][dt] = MFMA16(vf[dt][kk], pf0, O[g][0][dt]);
          O[g][1][dt] = MFMA16(vf[dt][kk], pf1, O[g][1][dt]);
        }
      }
    }
  }

  #pragma unroll
  for (int g=0; g<4; g++){
    int qg = wave + 8*g;
    if (qg >= 25) continue;
    #pragma unroll
    for (int qt=0;qt<2;qt++){
      float lsum = __shfl(O[g][qt][1][0], 32+li, 64);
      float inv = 1.0f/lsum;
      int ii = qg*32 + qt*16 + li;
      if (ii < NT) {
        int l = tok2l(br, ii, w);
        bf16* dst = out + ((size_t)(b*LL + l))*CC + coff;
        #pragma unroll
        for (int dt=0;dt<2;dt++)
          #pragma unroll
          for (int r=0;r<4;r++){
            int d = dt*16 + quad*4 + r;
            if (d < 24) dst[d] = (bf16)(O[g][qt][dt][r]*inv);
          }
      }
    }
  }
}

// ---------------- host launcher ----------------
extern "C" void kernel_launch(void* const* d_in, const int* in_sizes, int n_in,
                              void* d_out, int out_size, void* d_ws, size_t ws_size,
                              hipStream_t stream)
{
  const float* x    = (const float*)d_in[0];
  const float* n1w  = (const float*)d_in[1];
  const float* n1b  = (const float*)d_in[2];
  const float* qkvw = (const float*)d_in[3];
  const float* pjw  = (const float*)d_in[4];
  const float* pjb  = (const float*)d_in[5];
  const float* n2w  = (const float*)d_in[6];
  const float* n2b  = (const float*)d_in[7];
  const float* f1w  = (const float*)d_in[8];
  const float* f1b  = (const float*)d_in[9];
  const float* f2w  = (const float*)d_in[10];
  const float* f2b  = (const float*)d_in[11];

  char* p = (char*)d_ws;
  auto alloc = [&](size_t bytes){ void* r = (void*)p; p += (bytes + 255) & ~(size_t)255; return r; };
  bf16*  img  = (bf16*) alloc((size_t)25088*192*2);
  bf16*  qkvb = (bf16*) alloc((size_t)25088*576*2);
  bf16*  attn = (bf16*) alloc((size_t)25088*192*2);
  float* x2   = (float*)alloc((size_t)25088*192*4);
  bf16*  y    = (bf16*) alloc((size_t)25088*192*2);
  bf16*  hbuf = (bf16*) alloc((size_t)25088*768*2);
  float* posb = (float*)alloc((size_t)2*2899*4*4);
  bf16*  qkvw_b = (bf16*)alloc((size_t)576*192*2);
  bf16*  pjw_b  = (bf16*)alloc((size_t)192*192*2);
  bf16*  f1w_b  = (bf16*)alloc((size_t)768*192*2);
  bf16*  f2w_b  = (bf16*)alloc((size_t)192*768*2);
  float* outp = (float*)d_out;

  cvt_kernel<<<108,256,0,stream>>>(qkvw, qkvw_b, 576*192);
  cvt_kernel<<<36, 256,0,stream>>>(pjw,  pjw_b,  192*192);
  cvt_kernel<<<144,256,0,stream>>>(f1w,  f1w_b,  768*192);
  cvt_kernel<<<144,256,0,stream>>>(f2w,  f2w_b,  192*768);

  ln_kernel<<<6272,256,0,stream>>>(x, n1w, n1b, img);
  // qkv: N=576 (9 n-tiles), 56 strips x 448 rows (7 iters)
  gemm_regB<0,192,7><<<dim3(9,56),256,0,stream>>>(img, qkvw_b, 576,
      nullptr, nullptr, qkvb, nullptr);
  pos_mlp_kernel<<<23,256,0,stream>>>(
      (const float*)d_in[12], (const float*)d_in[13], (const float*)d_in[14],
      (const float*)d_in[15], (const float*)d_in[16], (const float*)d_in[17],
      (const float*)d_in[18], (const float*)d_in[19], (const float*)d_in[20],
      (const float*)d_in[21], (const float*)d_in[22], (const float*)d_in[23],
      (const float*)d_in[24], (const float*)d_in[25], posb);
  attn_kernel<<<256,512,0,stream>>>(qkvb, posb, attn);
  // proj: N=192 (3 n-tiles), 98 strips x 256 rows (4 iters)
  gemm_regB<1,192,4><<<dim3(3,98),256,0,stream>>>(attn, pjw_b, 192,
      pjb, x, nullptr, x2);
  ln_kernel<<<6272,256,0,stream>>>(x2, n2w, n2b, y);
  // fc1: N=768 (12 n-tiles), 56 strips x 448 rows (7 iters)
  gemm_regB<2,192,7><<<dim3(12,56),256,0,stream>>>(y, f1w_b, 768,
      f1b, nullptr, hbuf, nullptr);
  // fc2: K=768, N=192 (6 x 32-col tiles), 98 strips x 256 rows (4 iters)
  gemm_ldsB<4><<<dim3(6,98),256,0,stream>>>(hbuf, f2w_b, 192,
      f2b, x2, outp);
}

// Round 7
// 273.201 us; speedup vs baseline: 1.7922x; 1.3052x over previous
//
#include <hip/hip_runtime.h>

typedef __bf16 bf16;
typedef __bf16 bf16x8 __attribute__((ext_vector_type(8)));
typedef __bf16 bf16x4 __attribute__((ext_vector_type(4)));
typedef float  f32x4  __attribute__((ext_vector_type(4)));

#define MFMA16(A,B,C) __builtin_amdgcn_mfma_f32_16x16x32_bf16(A,B,C,0,0,0)
#define EXP2F(x) __builtin_amdgcn_exp2f(x)

static constexpr int BATCH = 2, HH = 112, WW = 112, CC = 192;
static constexpr int LL = HH*WW;              // 12544
static constexpr int NT = 784;                // tokens per window (112*7)
static constexpr float LOG2E = 1.4426950408889634f;
static constexpr float SCALE = 0.2041241452319315f;   // 24^-0.5
static constexpr float QSCALE = SCALE * LOG2E;        // folded for exp2 softmax

// ---------------- fused f32 -> bf16 conversion of all 4 weight mats ----------------
__global__ __launch_bounds__(256) void cvt4_kernel(
    const float* __restrict__ s0, const float* __restrict__ s1,
    const float* __restrict__ s2, const float* __restrict__ s3,
    bf16* __restrict__ d0, bf16* __restrict__ d1,
    bf16* __restrict__ d2, bf16* __restrict__ d3,
    int n0, int n1, int n2, int n3)
{
  int i = (blockIdx.x*256 + threadIdx.x)*4;
  const float* s; bf16* d;
  if      (i < n0)          { s = s0; d = d0; }
  else if (i < n0+n1)       { i -= n0; s = s1; d = d1; }
  else if (i < n0+n1+n2)    { i -= n0+n1; s = s2; d = d2; }
  else if (i < n0+n1+n2+n3) { i -= n0+n1+n2; s = s3; d = d3; }
  else return;
  float4 v = *(const float4*)(s+i);
  bf16x4 o; o[0]=(bf16)v.x; o[1]=(bf16)v.y; o[2]=(bf16)v.z; o[3]=(bf16)v.w;
  *(bf16x4*)(d+i) = o;
}

// ---------------- LayerNorm over C=192, one wave per row ----------------
__global__ __launch_bounds__(256) void ln_kernel(const float* __restrict__ in,
    const float* __restrict__ w, const float* __restrict__ b, bf16* __restrict__ out)
{
  int row  = blockIdx.x*4 + (threadIdx.x>>6);
  int lane = threadIdx.x & 63;
  size_t base = (size_t)row*CC;
  float x0=in[base+lane], x1=in[base+lane+64], x2=in[base+lane+128];
  float s = x0+x1+x2;
  #pragma unroll
  for (int o=32;o>=1;o>>=1) s += __shfl_xor(s,o,64);
  float mu = s*(1.0f/CC);
  float d0=x0-mu,d1=x1-mu,d2=x2-mu;
  float v = d0*d0+d1*d1+d2*d2;
  #pragma unroll
  for (int o=32;o>=1;o>>=1) v += __shfl_xor(v,o,64);
  float rstd = rsqrtf(v*(1.0f/CC)+1e-5f);
  out[base+lane]     = (bf16)(d0*rstd*w[lane]     +b[lane]);
  out[base+lane+64]  = (bf16)(d1*rstd*w[lane+64]  +b[lane+64]);
  out[base+lane+128] = (bf16)(d2*rstd*w[lane+128] +b[lane+128]);
}

// ------------- GEMM 64x64 tile, BK=96, 6 blocks/CU: out = A[M,K]*W[N,K]^T -------------
// EPI 0: qkv (scale q cols<192 by QSCALE, bf16 out), 1: proj(+bias+res_f32 -> f32)
// EPI 2: fc1(+bias+gelu, bf16 out),                  3: fc2(+bias+res_f32 -> f32)
template<int EPI, int K>
__global__ __launch_bounds__(256,6) void gemm_tile(
    const bf16* __restrict__ A, const bf16* __restrict__ W, int Nout,
    const float* __restrict__ bias, const float* __restrict__ resf,
    bf16* __restrict__ outb, float* __restrict__ outf)
{
  constexpr int LDW = 104;                    // 96 + 8 pad: 2-way-free banks
  __shared__ __align__(16) bf16 As[64*LDW];
  __shared__ __align__(16) bf16 Bs[64*LDW];
  int m0 = blockIdx.x*64, n0 = blockIdx.y*64;
  int tid = threadIdx.x;
  int lane = tid&63, li = lane&15, quad = lane>>4;
  int wave = tid>>6, wm = wave>>1, wn = wave&1;
  f32x4 acc[2][2] = {};
  for (int k0 = 0; k0 < K; k0 += 96) {
    __syncthreads();
    #pragma unroll
    for (int i=0;i<3;i++){
      int u = tid + 256*i;
      int row = u/12, cg = u - row*12;
      *(bf16x8*)&As[row*LDW + cg*8] = *(const bf16x8*)(A + (size_t)(m0+row)*K + k0 + cg*8);
      *(bf16x8*)&Bs[row*LDW + cg*8] = *(const bf16x8*)(W + (size_t)(n0+row)*K + k0 + cg*8);
    }
    __syncthreads();
    #pragma unroll
    for (int kk=0;kk<3;kk++){
      bf16x8 a0 = *(const bf16x8*)&As[(wm*32+li)*LDW    + kk*32 + quad*8];
      bf16x8 a1 = *(const bf16x8*)&As[(wm*32+16+li)*LDW + kk*32 + quad*8];
      bf16x8 b0 = *(const bf16x8*)&Bs[(wn*32+li)*LDW    + kk*32 + quad*8];
      bf16x8 b1 = *(const bf16x8*)&Bs[(wn*32+16+li)*LDW + kk*32 + quad*8];
      acc[0][0] = MFMA16(a0,b0,acc[0][0]);
      acc[0][1] = MFMA16(a0,b1,acc[0][1]);
      acc[1][0] = MFMA16(a1,b0,acc[1][0]);
      acc[1][1] = MFMA16(a1,b1,acc[1][1]);
    }
  }
  #pragma unroll
  for (int i=0;i<2;i++)
  #pragma unroll
  for (int j=0;j<2;j++){
    int col = n0 + wn*32 + j*16 + li;
    float bv = (EPI==0) ? 0.0f : bias[col];
    #pragma unroll
    for (int r=0;r<4;r++){
      int row = m0 + wm*32 + i*16 + quad*4 + r;
      float v = acc[i][j][r] + bv;
      size_t off = (size_t)row*Nout + col;
      if (EPI==0)      { if (col < CC) v *= QSCALE; outb[off] = (bf16)v; }
      else if (EPI==2) { v = 0.5f*v*(1.0f+erff(v*0.70710678118654752f)); outb[off] = (bf16)v; }
      else             { v += resf[off]; outf[off] = v; }
    }
  }
}

// ---------------- position-bias MLP (tiny) ----------------
__device__ __forceinline__ void ln6_relu(float* v, const float* w, const float* b){
  float mu=0;
  #pragma unroll
  for (int i=0;i<6;i++) mu += v[i];
  mu *= (1.0f/6.0f);
  float var=0;
  #pragma unroll
  for (int i=0;i<6;i++){ float d=v[i]-mu; var += d*d; }
  var *= (1.0f/6.0f);
  float rstd = rsqrtf(var + 1e-5f);
  #pragma unroll
  for (int i=0;i<6;i++){ float t=(v[i]-mu)*rstd*w[i]+b[i]; v[i] = t>0.f? t:0.f; }
}
__device__ __forceinline__ void fc66(const float* in, float* out, const float* w, const float* b){
  #pragma unroll
  for (int i=0;i<6;i++){
    float s=b[i];
    #pragma unroll
    for (int j=0;j<6;j++) s += in[j]*w[i*6+j];
    out[i]=s;
  }
}
__global__ __launch_bounds__(256) void pos_mlp_kernel(
    const float* pw, const float* pb, const float* l1w, const float* l1b,
    const float* f1w, const float* f1b, const float* l2w, const float* l2b,
    const float* f2w, const float* f2b, const float* l3w, const float* l3b,
    const float* f3w, const float* f3b, float* __restrict__ posb)
{
  int gid = blockIdx.x*256 + threadIdx.x;
  if (gid >= 2*2899) return;
  int br = gid / 2899, r = gid % 2899;
  int Hsp = br? 7:112, Wsp = br?112:7;
  int lpw = 2*Wsp-1;
  int iph = r / lpw, ipw = r % lpw;
  float c0 = (float)(iph - (Hsp-1)), c1 = (float)(ipw - (Wsp-1));
  float v[6], t[6];
  #pragma unroll
  for (int i=0;i<6;i++)
    v[i] = c0*pw[br*12+i*2] + c1*pw[br*12+i*2+1] + pb[br*6+i];
  ln6_relu(v, l1w+br*6, l1b+br*6); fc66(v, t, f1w+br*36, f1b+br*6);
  ln6_relu(t, l2w+br*6, l2b+br*6); fc66(t, v, f2w+br*36, f2b+br*6);
  ln6_relu(v, l3w+br*6, l3b+br*6);
  #pragma unroll
  for (int h=0;h<4;h++){
    float s=f3b[br*4+h];
    #pragma unroll
    for (int j=0;j<6;j++) s += v[j]*f3w[br*24+h*6+j];
    posb[(size_t)(br*2899 + r)*4 + h] = s;
  }
}

// ---------------- flash attention, one block per (br,b,window,head) ----------------
__device__ __forceinline__ int tok2l(int br, int t, int w) {
  if (br == 0) return (t/7)*WW + w*7 + (t - (t/7)*7);
  int th = t/112; return (w*7 + th)*WW + (t - th*112);
}
__device__ __forceinline__ int acode(int br, int t) {
  int rh = br ? (((t>>4)*18725)>>17) : ((t*18725)>>17);   // t/112 or t/7, exact for t<784
  return t + (br ? 111 : 6) * rh;
}

__global__ __launch_bounds__(512) void attn_kernel(const bf16* __restrict__ qkv,
    const float* __restrict__ posb, bf16* __restrict__ out)
{
  __shared__ __align__(16) bf16 Ks[832*40];    // [key 832][d 40], d>=24 zero, rows>=784 zero
  __shared__ __align__(16) bf16 Vt[32*840];    // [d 32][key 840], row 24 = ones (cols<784)
  __shared__ __align__(16) bf16 Ps[8][32*72];  // per-wave P [i 32][key 72]
  __shared__ __align__(16) bf16 postab[2904];  // pos table (x log2e) for this (br,h)
  int bid = blockIdx.x;
  int br = bid & 1, h = (bid>>1)&3, w = (bid>>3)&15, b = bid>>7;  // (br,h)=bid&7 -> XCD
  int tid = threadIdx.x;
  int lane = tid&63, li = lane&15, quad = lane>>4, wave = tid>>6;
  size_t qbase = (size_t)b*LL*576;
  int coff = br*96 + h*24;
  for (int c = tid; c < (832*40)/8; c += 512) ((int4*)Ks)[c] = make_int4(0,0,0,0);
  for (int c = tid; c < (32*840)/8; c += 512) ((int4*)Vt)[c] = make_int4(0,0,0,0);
  __syncthreads();
  for (int c = tid; c < NT*3; c += 512) {
    int j = c/3, p = c - j*3;
    int l = tok2l(br, j, w);
    *(bf16x8*)&Ks[j*40 + p*8] =
        *(const bf16x8*)(qkv + qbase + (size_t)l*576 + 192 + coff + p*8);
  }
  for (int j = tid; j < NT; j += 512) {
    int l = tok2l(br, j, w);
    const bf16* src = qkv + qbase + (size_t)l*576 + 384 + coff;
    bf16x8 v0 = *(const bf16x8*)src;
    bf16x8 v1 = *(const bf16x8*)(src+8);
    bf16x8 v2 = *(const bf16x8*)(src+16);
    #pragma unroll
    for (int d=0; d<8; d++){
      Vt[d*840 + j]      = v0[d];
      Vt[(8+d)*840 + j]  = v1[d];
      Vt[(16+d)*840 + j] = v2[d];
    }
    Vt[24*840 + j] = (bf16)1.0f;
  }
  {
    const float* pb = posb + (size_t)br*2899*4 + h;
    for (int r = tid; r < 2904; r += 512)
      postab[r] = (bf16)(r < 2899 ? pb[(size_t)r*4]*LOG2E : 0.0f);
  }
  __syncthreads();

  bf16x8 qf[4][2]; int pai[4][2];
  #pragma unroll
  for (int g=0; g<4; g++){
    int qg = wave + 8*g;
    if (qg >= 25) continue;
    #pragma unroll
    for (int t=0;t<2;t++){
      int ii = qg*32 + t*16 + li;
      int ic = ii < NT ? ii : NT-1;
      int l = tok2l(br, ic, w);
      qf[g][t] = *(const bf16x8*)(qkv + qbase + (size_t)l*576 + coff + quad*8);
      pai[g][t] = acode(br, ic) + 1449;
    }
  }
  f32x4 O[4][2][2] = {};

  for (int kc = 0; kc < 13; kc++) {
    int kb = kc*64;
    int ajv[16];
    #pragma unroll
    for (int kt=0;kt<4;kt++)
      #pragma unroll
      for (int r=0;r<4;r++){
        int j = kb + kt*16 + quad*4 + r;
        int jc = j < NT ? j : NT-1;
        ajv[kt*4+r] = acode(br, jc);
      }
    bf16x8 kf[4];
    #pragma unroll
    for (int kt=0;kt<4;kt++)
      kf[kt] = *(const bf16x8*)&Ks[(kb + kt*16 + li)*40 + quad*8];
    bf16x8 vf[2][2];
    #pragma unroll
    for (int dt=0;dt<2;dt++)
      #pragma unroll
      for (int kk=0;kk<2;kk++)
        vf[dt][kk] = *(const bf16x8*)&Vt[(dt*16+li)*840 + kb + kk*32 + quad*8];

    #pragma unroll
    for (int g=0; g<4; g++){
      if (wave + 8*g >= 25) continue;
      // bias preloaded into MFMA C operand (no mask needed: zero K-rows / zero
      // V-cols make j>=784 contributions vanish from numerator AND denominator)
      f32x4 S0[4], S1[4];
      #pragma unroll
      for (int kt=0;kt<4;kt++)
        #pragma unroll
        for (int r=0;r<4;r++){
          int n = kt*4+r;
          S0[kt][r] = (float)postab[pai[g][0] - ajv[n]];
          S1[kt][r] = (float)postab[pai[g][1] - ajv[n]];
        }
      #pragma unroll
      for (int kt=0;kt<4;kt++){
        S0[kt] = MFMA16(kf[kt], qf[g][0], S0[kt]);   // S^T = K*Q^T + bias
        S1[kt] = MFMA16(kf[kt], qf[g][1], S1[kt]);
      }
      #pragma unroll
      for (int kt=0;kt<4;kt++){
        bf16x4 p0, p1;
        #pragma unroll
        for (int r=0;r<4;r++){
          p0[r] = (bf16)EXP2F(S0[kt][r]);
          p1[r] = (bf16)EXP2F(S1[kt][r]);
        }
        *(bf16x4*)&Ps[wave][li*72      + kt*16 + quad*4] = p0;
        *(bf16x4*)&Ps[wave][(16+li)*72 + kt*16 + quad*4] = p1;
      }
      asm volatile("s_waitcnt lgkmcnt(0)" ::: "memory");
      #pragma unroll
      for (int kk=0;kk<2;kk++){
        bf16x8 pf0 = *(const bf16x8*)&Ps[wave][li*72      + kk*32 + quad*8];
        bf16x8 pf1 = *(const bf16x8*)&Ps[wave][(16+li)*72 + kk*32 + quad*8];
        #pragma unroll
        for (int dt=0;dt<2;dt++){
          O[g][0][dt] = MFMA16(vf[dt][kk], pf0, O[g][0][dt]);
          O[g][1][dt] = MFMA16(vf[dt][kk], pf1, O[g][1][dt]);
        }
      }
    }
  }

  #pragma unroll
  for (int g=0; g<4; g++){
    int qg = wave + 8*g;
    if (qg >= 25) continue;
    #pragma unroll
    for (int qt=0;qt<2;qt++){
      float lsum = __shfl(O[g][qt][1][0], 32+li, 64);
      float inv = 1.0f/lsum;
      int ii = qg*32 + qt*16 + li;
      if (ii < NT) {
        int l = tok2l(br, ii, w);
        bf16* dst = out + ((size_t)(b*LL + l))*CC + coff;
        #pragma unroll
        for (int dt=0;dt<2;dt++)
          #pragma unroll
          for (int r=0;r<4;r++){
            int d = dt*16 + quad*4 + r;
            if (d < 24) dst[d] = (bf16)(O[g][qt][dt][r]*inv);
          }
      }
    }
  }
}

// ---------------- host launcher ----------------
extern "C" void kernel_launch(void* const* d_in, const int* in_sizes, int n_in,
                              void* d_out, int out_size, void* d_ws, size_t ws_size,
                              hipStream_t stream)
{
  const float* x    = (const float*)d_in[0];
  const float* n1w  = (const float*)d_in[1];
  const float* n1b  = (const float*)d_in[2];
  const float* qkvw = (const float*)d_in[3];
  const float* pjw  = (const float*)d_in[4];
  const float* pjb  = (const float*)d_in[5];
  const float* n2w  = (const float*)d_in[6];
  const float* n2b  = (const float*)d_in[7];
  const float* f1w  = (const float*)d_in[8];
  const float* f1b  = (const float*)d_in[9];
  const float* f2w  = (const float*)d_in[10];
  const float* f2b  = (const float*)d_in[11];

  char* p = (char*)d_ws;
  auto alloc = [&](size_t bytes){ void* r = (void*)p; p += (bytes + 255) & ~(size_t)255; return r; };
  bf16*  img  = (bf16*) alloc((size_t)25088*192*2);
  bf16*  qkvb = (bf16*) alloc((size_t)25088*576*2);
  bf16*  attn = (bf16*) alloc((size_t)25088*192*2);
  float* x2   = (float*)alloc((size_t)25088*192*4);
  bf16*  y    = (bf16*) alloc((size_t)25088*192*2);
  bf16*  hbuf = (bf16*) alloc((size_t)25088*768*2);
  float* posb = (float*)alloc((size_t)2*2899*4*4);
  bf16*  qkvw_b = (bf16*)alloc((size_t)576*192*2);
  bf16*  pjw_b  = (bf16*)alloc((size_t)192*192*2);
  bf16*  f1w_b  = (bf16*)alloc((size_t)768*192*2);
  bf16*  f2w_b  = (bf16*)alloc((size_t)192*768*2);
  float* outp = (float*)d_out;

  cvt4_kernel<<<432,256,0,stream>>>(qkvw, pjw, f1w, f2w,
      qkvw_b, pjw_b, f1w_b, f2w_b, 576*192, 192*192, 768*192, 192*768);

  ln_kernel<<<6272,256,0,stream>>>(x, n1w, n1b, img);
  gemm_tile<0,192><<<dim3(392,9),256,0,stream>>>(img, qkvw_b, 576,
      nullptr, nullptr, qkvb, nullptr);
  pos_mlp_kernel<<<23,256,0,stream>>>(
      (const float*)d_in[12], (const float*)d_in[13], (const float*)d_in[14],
      (const float*)d_in[15], (const float*)d_in[16], (const float*)d_in[17],
      (const float*)d_in[18], (const float*)d_in[19], (const float*)d_in[20],
      (const float*)d_in[21], (const float*)d_in[22], (const float*)d_in[23],
      (const float*)d_in[24], (const float*)d_in[25], posb);
  attn_kernel<<<256,512,0,stream>>>(qkvb, posb, attn);
  gemm_tile<1,192><<<dim3(392,3),256,0,stream>>>(attn, pjw_b, 192,
      pjb, x, nullptr, x2);
  ln_kernel<<<6272,256,0,stream>>>(x2, n2w, n2b, y);
  gemm_tile<2,192><<<dim3(392,12),256,0,stream>>>(y, f1w_b, 768,
      f1b, nullptr, hbuf, nullptr);
  gemm_tile<3,768><<<dim3(392,3),256,0,stream>>>(hbuf, f2w_b, 192,
      f2b, x2, nullptr, outp);
}